// Round 6
// baseline (234.062 us; speedup 1.0000x reference)
//
#include <hip/hip_runtime.h>
#include <cstdint>

#define B_SZ 2048
#define T_SZ 512
#define F_SZ 64
#define NG   12            // 4*H, H=3
#define BPB  8             // batch rows per block
#define TCH  16            // timesteps per chunk
#define NCHK (T_SZ / TCH)  // 32
#define NBLK (B_SZ / BPB)  // 256
#define NTHR 192           // wave0 = scan, waves 1-2 = compute
#define NSLOT (BPB * TCH * 16)  // 2048 float4 slots per x-chunk
#define ZSTR 100           // zbuf t-stride in floats (96 + 4 pad: bank-spread)

#define L2E 1.4426950408889634f

__device__ __forceinline__ float fast_rcp(float x) { return __builtin_amdgcn_rcpf(x); }
__device__ __forceinline__ float exp2h(float x)    { return __builtin_amdgcn_exp2f(x); }
__device__ __forceinline__ float sigm_s(float zs)  { return fast_rcp(1.0f + exp2h(zs)); }
__device__ __forceinline__ float tanh_s(float zs)  { return fmaf(2.0f, fast_rcp(1.0f + exp2h(zs)), -1.0f); }
__device__ __forceinline__ float sigm_n(float x)   { return sigm_s(x * (-L2E)); }
__device__ __forceinline__ float tanh_n(float x)   { return tanh_s(x * (-2.0f * L2E)); }

template<int CTRL>
__device__ __forceinline__ float qperm(float v) {
    return __int_as_float(__builtin_amdgcn_mov_dpp(__float_as_int(v), CTRL, 0xF, 0xF, false));
}
#define QPA 9    // lane k <- src[{1,2,0,0}[k]]  -> h_{(m+1)%3}
#define QPB 82   // lane k <- src[{2,0,1,1}[k]]  -> h_{(m+2)%3}

__global__ __launch_bounds__(NTHR) void lstm_fused(const float* __restrict__ x,
                                                   const float* __restrict__ W,
                                                   const float* __restrict__ U,
                                                   const float* __restrict__ bias,
                                                   const float* __restrict__ Wd,
                                                   const float* __restrict__ bdp,
                                                   float* __restrict__ out) {
    __shared__ float xbuf[2][BPB * TCH * F_SZ];   // 64 KB: rows of 16 float4, XOR-swizzled content
    __shared__ float zbuf[2][TCH * ZSTR];         // 12.5 KB: [t][b*12] with padded t-stride
    __shared__ float Ws[F_SZ * NG];               // scaled/reordered W (p = m*4+q <- col q*3+m)
    __shared__ float bs[NG];

    const int tid = threadIdx.x;
    const int b0  = blockIdx.x * BPB;

    // ---- stage weights (scaled by -L2E / -2*L2E so gates are pure exp2 forms) ----
    for (int i = tid; i < F_SZ * NG; i += NTHR) {
        const int f = i / NG, p = i - f * NG;
        const int mm = p >> 2, q = p & 3;
        const float sc = (q == 2) ? (-2.0f * L2E) : (-L2E);
        Ws[i] = W[f * NG + q * 3 + mm] * sc;
    }
    if (tid < NG) {
        const int mm = tid >> 2, q = tid & 3;
        const float sc = (q == 2) ? (-2.0f * L2E) : (-L2E);
        bs[tid] = bias[q * 3 + mm] * sc;
    }

    // ---- scan-lane constants (wave 0 only uses them) ----
    const int lk = tid & 3;
    const int m  = (lk < 3) ? lk : 2;
    const int mn = (m + 1 == 3) ? 0 : m + 1;
    const int mp = (m + 2 >= 3) ? m - 1 : m + 2;
    const int e  = (tid >> 2) & 7;         // lanes 32-63 mirror elems 0-7 (harmless)
    float u_own[4], u_nxt[4], u_prv[4];
    if (tid < 64) {
        #pragma unroll
        for (int q = 0; q < 4; ++q) {
            const float sc = (q == 2) ? (-2.0f * L2E) : (-L2E);
            const int col = q * 3 + m;
            u_own[q] = U[m  * NG + col] * sc;
            u_nxt[q] = U[mn * NG + col] * sc;
            u_prv[q] = U[mp * NG + col] * sc;
        }
    }
    float h = 0.0f, c = 0.0f, hA = 0.0f, hB = 0.0f;

    // ---- staging helpers (reg-staged; LDS slot s holds x float4 (s&15)^(row&15) of row s>>4) ----
    float4 stg[11];
    auto stage_load = [&](int ck) {
        const int t0 = ck * TCH;
        #pragma unroll
        for (int p = 0; p < 11; ++p) {
            const int slot = p * NTHR + tid;
            if (slot < NSLOT) {
                const int row = slot >> 4, s4 = slot & 15;
                const int src4 = s4 ^ (row & 15);
                stg[p] = *reinterpret_cast<const float4*>(
                    x + ((size_t)(b0 + (row >> 4)) * T_SZ + (t0 + (row & 15))) * F_SZ + src4 * 4);
            }
        }
    };
    auto stage_store = [&](int xb) {
        #pragma unroll
        for (int p = 0; p < 11; ++p) {
            const int slot = p * NTHR + tid;
            if (slot < NSLOT)
                *reinterpret_cast<float4*>(&xbuf[xb][slot * 4]) = stg[p];
        }
    };

    auto comp = [&](const float4& z4) {
        const float z0 = fmaf(h, u_own[0], z4.x) + fmaf(hA, u_nxt[0], hB * u_prv[0]);
        const float z1 = fmaf(h, u_own[1], z4.y) + fmaf(hA, u_nxt[1], hB * u_prv[1]);
        const float z2 = fmaf(h, u_own[2], z4.z) + fmaf(hA, u_nxt[2], hB * u_prv[2]);
        const float z3 = fmaf(h, u_own[3], z4.w) + fmaf(hA, u_nxt[3], hB * u_prv[3]);
        const float ai = sigm_s(z0);
        const float af = sigm_s(z1);
        const float ag = tanh_s(z2);
        const float ao = sigm_s(z3);
        c = fmaf(af, c, ai * ag);
        h = ao * tanh_n(c);
        hA = qperm<QPA>(h);
        hB = qperm<QPB>(h);
    };

    // ---- prologue: stage chunk 0 ----
    stage_load(0);
    stage_store(0);
    __syncthreads();

    // ---- main pipeline: stage(k+1) || compute z(k) || scan(k-1) ----
    for (int k = 0; k < NCHK; ++k) {
        const int xb = k & 1;
        if (k + 1 < NCHK) stage_load(k + 1);

        if (tid >= 64) {
            // compute: one (b,t) row per thread; row == cid
            const int cid = tid - 64;            // 0..127
            const int cb = cid >> 4, ctt = cid & 15;
            float acc[NG];
            #pragma unroll
            for (int p = 0; p < NG; ++p) acc[p] = bs[p];
            const float* xb_ = xbuf[xb];
            #pragma unroll
            for (int j = 0; j < 16; ++j) {
                const int s4 = j ^ (cid & 15);
                const float4 xv = *reinterpret_cast<const float4*>(&xb_[(cid * 16 + s4) * 4]);
                #pragma unroll
                for (int jj = 0; jj < 4; ++jj) {
                    const float xsv = (jj == 0) ? xv.x : (jj == 1) ? xv.y : (jj == 2) ? xv.z : xv.w;
                    const float* wr = &Ws[(j * 4 + jj) * NG];
                    #pragma unroll
                    for (int p = 0; p < NG; ++p) acc[p] = fmaf(xsv, wr[p], acc[p]);
                }
            }
            float* zp = &zbuf[xb][ctt * ZSTR + cb * NG];
            *reinterpret_cast<float4*>(zp + 0) = make_float4(acc[0], acc[1], acc[2],  acc[3]);
            *reinterpret_cast<float4*>(zp + 4) = make_float4(acc[4], acc[5], acc[6],  acc[7]);
            *reinterpret_cast<float4*>(zp + 8) = make_float4(acc[8], acc[9], acc[10], acc[11]);
        } else if (k > 0) {
            // scan chunk k-1 from zbuf[xb^1]
            const float* zp0 = &zbuf[xb ^ 1][e * NG + m * 4];
            float4 zn = *reinterpret_cast<const float4*>(zp0);
            #pragma unroll
            for (int t = 0; t < TCH; ++t) {
                const float4 zc = zn;
                if (t + 1 < TCH) zn = *reinterpret_cast<const float4*>(zp0 + (t + 1) * ZSTR);
                comp(zc);
            }
        }

        if (k + 1 < NCHK) stage_store(xb ^ 1);
        __syncthreads();
    }

    // ---- epilogue: scan last chunk (zbuf[(NCHK-1)&1]) ----
    if (tid < 64) {
        const float* zp0 = &zbuf[(NCHK - 1) & 1][e * NG + m * 4];
        float4 zn = *reinterpret_cast<const float4*>(zp0);
        #pragma unroll
        for (int t = 0; t < TCH; ++t) {
            const float4 zc = zn;
            if (t + 1 < TCH) zn = *reinterpret_cast<const float4*>(zp0 + (t + 1) * ZSTR);
            comp(zc);
        }
        // dense head: lane k==0 of each quad holds (h, hA=h_next, hB=h_prev)
        if (tid < 32 && lk == 0) {
            const float logit = bdp[0] + h * Wd[m] + hA * Wd[mn] + hB * Wd[mp];
            out[b0 + e] = sigm_n(logit);
        }
    }
}

extern "C" void kernel_launch(void* const* d_in, const int* in_sizes, int n_in,
                              void* d_out, int out_size, void* d_ws, size_t ws_size,
                              hipStream_t stream) {
    (void)in_sizes; (void)n_in; (void)out_size; (void)d_ws; (void)ws_size;
    const float* x  = (const float*)d_in[0];
    const float* W  = (const float*)d_in[1];
    const float* U  = (const float*)d_in[2];
    const float* b  = (const float*)d_in[3];
    const float* Wd = (const float*)d_in[4];
    const float* bd = (const float*)d_in[5];
    float* out = (float*)d_out;

    lstm_fused<<<NBLK, NTHR, 0, stream>>>(x, W, U, b, Wd, bd, out);
}

// Round 7
// 131.316 us; speedup vs baseline: 1.7824x; 1.7824x over previous
//
#include <hip/hip_runtime.h>
#include <cstdint>

#define B_SZ 2048
#define T_SZ 512
#define F_SZ 64
#define NG   12            // 4*H, H=3
#define BPB  8             // batch rows per block
#define TCH  16            // timesteps per chunk
#define NCHK (T_SZ / TCH)  // 32
#define NBLK (B_SZ / BPB)  // 256
#define NTHR 256           // wave0 scan, waves1-2 compute, wave3 staging helper
#define ROWS (BPB * TCH)   // 128 (b,t) rows per chunk
#define ZSTR 100           // zbuf t-stride in floats (96 + 4 pad)

#define L2E 1.4426950408889634f

__device__ __forceinline__ float fast_rcp(float x) { return __builtin_amdgcn_rcpf(x); }
__device__ __forceinline__ float exp2h(float x)    { return __builtin_amdgcn_exp2f(x); }
__device__ __forceinline__ float sigm_s(float zs)  { return fast_rcp(1.0f + exp2h(zs)); }
__device__ __forceinline__ float tanh_s(float zs)  { return fmaf(2.0f, fast_rcp(1.0f + exp2h(zs)), -1.0f); }
__device__ __forceinline__ float sigm_n(float x)   { return sigm_s(x * (-L2E)); }
__device__ __forceinline__ float tanh_n(float x)   { return tanh_s(x * (-2.0f * L2E)); }

template<int CTRL>
__device__ __forceinline__ float qperm(float v) {
    return __int_as_float(__builtin_amdgcn_mov_dpp(__float_as_int(v), CTRL, 0xF, 0xF, false));
}
#define QPA 9    // lane k <- src[{1,2,0,0}[k]]  -> h_{(m+1)%3}
#define QPB 82   // lane k <- src[{2,0,1,1}[k]]  -> h_{(m+2)%3}

// direct HBM -> LDS, 16B per lane, LDS dest = wave-uniform base + lane*16
__device__ __forceinline__ void gload16(const float* g, float* l) {
    __builtin_amdgcn_global_load_lds(
        (const __attribute__((address_space(1))) void*)g,
        (__attribute__((address_space(3))) void*)l, 16, 0, 0);
}

__global__ __launch_bounds__(NTHR) void lstm_fused(const float* __restrict__ x,
                                                   const float* __restrict__ W,
                                                   const float* __restrict__ U,
                                                   const float* __restrict__ bias,
                                                   const float* __restrict__ Wd,
                                                   const float* __restrict__ bdp,
                                                   float* __restrict__ out) {
    __shared__ float xbuf[2][ROWS * F_SZ];   // 2 x 32 KB, slot s = 16B: row = s>>4, holds x float4 (s&15)^(row&15)
    __shared__ float zbuf[2][TCH * ZSTR];    // [t][b*12], padded stride
    __shared__ float Ws[F_SZ * NG];          // scaled/reordered W (p = m*4+q <- col q*3+m)
    __shared__ float bs[NG];

    const int tid = threadIdx.x;
    const int wv  = tid >> 6;
    const int ln  = tid & 63;
    const int b0  = blockIdx.x * BPB;

    // ---- stage weights (scaled so every gate is a pure exp2 form) ----
    for (int i = tid; i < F_SZ * NG; i += NTHR) {
        const int f = i / NG, p = i - f * NG;
        const int mm = p >> 2, q = p & 3;
        const float sc = (q == 2) ? (-2.0f * L2E) : (-L2E);
        Ws[i] = W[f * NG + q * 3 + mm] * sc;
    }
    if (tid < NG) {
        const int mm = tid >> 2, q = tid & 3;
        const float sc = (q == 2) ? (-2.0f * L2E) : (-L2E);
        bs[tid] = bias[q * 3 + mm] * sc;
    }

    // ---- scan-lane constants (wave 0 only) ----
    const int lk = ln & 3;
    const int m  = (lk < 3) ? lk : 2;
    const int mn = (m + 1 == 3) ? 0 : m + 1;
    const int mp = (m + 2 >= 3) ? m - 1 : m + 2;
    const int e  = (ln >> 2) & 7;            // 8 elements; lanes 32-63 mirror (harmless)
    float u_own[4], u_nxt[4], u_prv[4];
    if (wv == 0) {
        #pragma unroll
        for (int q = 0; q < 4; ++q) {
            const float sc = (q == 2) ? (-2.0f * L2E) : (-L2E);
            const int col = q * 3 + m;
            u_own[q] = U[m  * NG + col] * sc;
            u_nxt[q] = U[mn * NG + col] * sc;
            u_prv[q] = U[mp * NG + col] * sc;
        }
    }
    float h = 0.0f, c = 0.0f, hA = 0.0f, hB = 0.0f;

    // ---- staging: 32 wave-instructions cover 2048 slots; pre-swizzled global src ----
    auto stage = [&](int ck, int buf) {
        const int t0 = ck * TCH;
        #pragma unroll
        for (int call = 0; call < 8; ++call) {
            const int grp  = call * 4 + wv;        // 64-slot group, 0..31
            const int s    = grp * 64 + ln;        // slot
            const int row  = s >> 4;
            const int src4 = (s & 15) ^ (row & 15);
            const float* g = x + ((size_t)(b0 + (row >> 4)) * T_SZ + (t0 + (row & 15))) * F_SZ + src4 * 4;
            gload16(g, &xbuf[buf][grp * 256]);     // base wave-uniform; lane*16 implicit
        }
    };

    auto comp = [&](const float4& z4) {
        const float z0 = fmaf(h, u_own[0], z4.x) + fmaf(hA, u_nxt[0], hB * u_prv[0]);
        const float z1 = fmaf(h, u_own[1], z4.y) + fmaf(hA, u_nxt[1], hB * u_prv[1]);
        const float z2 = fmaf(h, u_own[2], z4.z) + fmaf(hA, u_nxt[2], hB * u_prv[2]);
        const float z3 = fmaf(h, u_own[3], z4.w) + fmaf(hA, u_nxt[3], hB * u_prv[3]);
        const float ai = sigm_s(z0);
        const float af = sigm_s(z1);
        const float ag = tanh_s(z2);
        const float ao = sigm_s(z3);
        c = fmaf(af, c, ai * ag);
        h = ao * tanh_n(c);
        hA = qperm<QPA>(h);
        hB = qperm<QPB>(h);
    };

    auto scan16 = [&](const float* zb) {
        const float* zp0 = zb + e * NG + m * 4;
        float4 zn = *reinterpret_cast<const float4*>(zp0);
        #pragma unroll
        for (int t = 0; t < TCH; ++t) {
            const float4 zc = zn;
            if (t + 1 < TCH) zn = *reinterpret_cast<const float4*>(zp0 + (t + 1) * ZSTR);
            comp(zc);
        }
    };

    // ---- prologue ----
    stage(0, 0);
    __syncthreads();   // vmcnt(0) drained by compiler before barrier

    // ---- main pipeline: stage(k+1) || compute z(k) || scan(k-1) ----
    for (int k = 0; k < NCHK; ++k) {
        const int cur = k & 1;
        if (k + 1 < NCHK) stage(k + 1, cur ^ 1);

        if (wv == 1 || wv == 2) {
            const int cid = tid - 64;            // 0..127: row = (b, t)
            const int cb = cid >> 4, ctt = cid & 15;
            float acc[NG];
            #pragma unroll
            for (int p = 0; p < NG; ++p) acc[p] = bs[p];
            const float* xb_ = xbuf[cur];
            #pragma unroll
            for (int j = 0; j < 16; ++j) {
                const int s4 = j ^ (cid & 15);
                const float4 xv = *reinterpret_cast<const float4*>(&xb_[(cid * 16 + s4) * 4]);
                #pragma unroll
                for (int jj = 0; jj < 4; ++jj) {
                    const float xsv = (jj == 0) ? xv.x : (jj == 1) ? xv.y : (jj == 2) ? xv.z : xv.w;
                    const float* wr = &Ws[(j * 4 + jj) * NG];
                    #pragma unroll
                    for (int p = 0; p < NG; ++p) acc[p] = fmaf(xsv, wr[p], acc[p]);
                }
            }
            float* zp = &zbuf[cur][ctt * ZSTR + cb * NG];
            *reinterpret_cast<float4*>(zp + 0) = make_float4(acc[0], acc[1], acc[2],  acc[3]);
            *reinterpret_cast<float4*>(zp + 4) = make_float4(acc[4], acc[5], acc[6],  acc[7]);
            *reinterpret_cast<float4*>(zp + 8) = make_float4(acc[8], acc[9], acc[10], acc[11]);
        } else if (wv == 0 && k > 0) {
            scan16(zbuf[cur ^ 1]);
        }
        __syncthreads();   // z(k) visible; xbuf[cur^1] fully landed (vmcnt drain)
    }

    // ---- epilogue: scan the last chunk, then dense head ----
    if (wv == 0) {
        scan16(zbuf[(NCHK - 1) & 1]);
        if (ln < 32 && lk == 0) {
            const float logit = bdp[0] + h * Wd[m] + hA * Wd[mn] + hB * Wd[mp];
            out[b0 + e] = sigm_n(logit);
        }
    }
}

extern "C" void kernel_launch(void* const* d_in, const int* in_sizes, int n_in,
                              void* d_out, int out_size, void* d_ws, size_t ws_size,
                              hipStream_t stream) {
    (void)in_sizes; (void)n_in; (void)out_size; (void)d_ws; (void)ws_size;
    const float* x  = (const float*)d_in[0];
    const float* W  = (const float*)d_in[1];
    const float* U  = (const float*)d_in[2];
    const float* b  = (const float*)d_in[3];
    const float* Wd = (const float*)d_in[4];
    const float* bd = (const float*)d_in[5];
    float* out = (float*)d_out;

    lstm_fused<<<NBLK, NTHR, 0, stream>>>(x, W, U, b, Wd, bd, out);
}

// Round 8
// 95.196 us; speedup vs baseline: 2.4587x; 1.3794x over previous
//
#include <hip/hip_runtime.h>
#include <hip/hip_bf16.h>
#include <cstdint>

#define B_SZ 2048
#define T_SZ 512
#define F_SZ 64
#define BPB  4              // batch rows per block
#define TCH  32             // timesteps per chunk
#define NCHK (T_SZ / TCH)   // 16
#define NBLK (B_SZ / BPB)   // 512 -> 2 blocks/CU
#define NTHR 128            // wave0 = scan, wave1 = MFMA; both stage
#define ROWS (BPB * TCH)    // 128 rows (b,t) per chunk
#define MT   (ROWS / 16)    // 8 M-tiles
#define NPC  (ROWS * 16)    // 2048 float4 staging pieces per chunk
#define PPT  (NPC / NTHR)   // 16 pieces per thread
#define TSTR 84             // zbuf t-stride (floats)
#define ESTR 20             // zbuf b-elem stride (floats)

#define L2E 1.4426950408889634f

typedef __attribute__((ext_vector_type(8))) short short8;
typedef __attribute__((ext_vector_type(4))) float f32x4;

__device__ __forceinline__ float fast_rcp(float x) { return __builtin_amdgcn_rcpf(x); }
__device__ __forceinline__ float exp2h(float x)    { return __builtin_amdgcn_exp2f(x); }
__device__ __forceinline__ float sigm_s(float zs)  { return fast_rcp(1.0f + exp2h(zs)); }
__device__ __forceinline__ float tanh_s(float zs)  { return fmaf(2.0f, fast_rcp(1.0f + exp2h(zs)), -1.0f); }
__device__ __forceinline__ float sigm_n(float x)   { return sigm_s(x * (-L2E)); }
__device__ __forceinline__ float tanh_n(float x)   { return tanh_s(x * (-2.0f * L2E)); }

__device__ __forceinline__ unsigned short f2bf(float f) {
    __hip_bfloat16 h = (__hip_bfloat16)f;   // RNE
    return *reinterpret_cast<unsigned short*>(&h);
}

template<int CTRL>
__device__ __forceinline__ float qperm(float v) {
    return __int_as_float(__builtin_amdgcn_mov_dpp(__float_as_int(v), CTRL, 0xF, 0xF, false));
}
#define QPA 9    // lane k <- src[{1,2,0,0}[k]]  -> h_{(m+1)%3}
#define QPB 82   // lane k <- src[{2,0,1,1}[k]]  -> h_{(m+2)%3}

__global__ __launch_bounds__(NTHR) void lstm_mfma(const float* __restrict__ x,
                                                  const float* __restrict__ W,
                                                  const float* __restrict__ U,
                                                  const float* __restrict__ bias,
                                                  const float* __restrict__ Wd,
                                                  const float* __restrict__ bdp,
                                                  float* __restrict__ out) {
    // A-fragment-ordered x (bf16): per (Mtile,Ktile): 64 lanes x 16B
    __shared__ unsigned int xfrag[2][MT * 2 * 256];   // 2 x 16 KB
    __shared__ float zbuf[2][TCH * TSTR];             // 2 x 10.75 KB

    const int tid = threadIdx.x;
    const int wv  = tid >> 6;
    const int ln  = tid & 63;
    const int b0  = blockIdx.x * BPB;

    // ---- per-lane gate mapping (gate p = mm*4+q <- W col q*3+mm), scaled ----
    const int n  = ln & 15;                 // MFMA col = gate index (12 real + 4 pad)
    const int q  = n & 3, mm = n >> 2;
    const float sc = (q == 2) ? (-2.0f * L2E) : (-L2E);

    // ---- B-fragments: W stationary in VGPRs (loaded once) ----
    short8 bfrag[2];
    #pragma unroll
    for (int kt = 0; kt < 2; ++kt) {
        short8 s;
        #pragma unroll
        for (int e = 0; e < 8; ++e) {
            const int h = e >> 2, j = e & 3;
            const int kk = kt * 32 + h * 16 + 4 * (ln >> 4) + j;   // f index
            const float w = (n < 12) ? W[kk * 12 + q * 3 + mm] * sc : 0.0f;
            s[e] = (short)f2bf(w);
        }
        bfrag[kt] = s;
    }
    const float bias_s = (n < 12) ? bias[q * 3 + mm] * sc : 0.0f;

    // ---- scan-lane constants (wave 0, lanes 0..15 meaningful) ----
    const int lk = ln & 3;
    const int m  = (lk < 3) ? lk : 2;
    const int mn = (m + 1 == 3) ? 0 : m + 1;
    const int mp = (m + 2 >= 3) ? m - 1 : m + 2;
    const int e8 = (ln >> 2) & 3;           // batch elem 0..3 (dups beyond lane 15)
    float u_own[4], u_nxt[4], u_prv[4];
    #pragma unroll
    for (int qq = 0; qq < 4; ++qq) {
        const float scq = (qq == 2) ? (-2.0f * L2E) : (-L2E);
        const int col = qq * 3 + m;
        u_own[qq] = U[m  * 12 + col] * scq;
        u_nxt[qq] = U[mn * 12 + col] * scq;
        u_prv[qq] = U[mp * 12 + col] * scq;
    }
    float h = 0.0f, c = 0.0f, hA = 0.0f, hB = 0.0f;

    auto comp = [&](const float4& z4) {
        const float z0 = fmaf(h, u_own[0], z4.x) + fmaf(hA, u_nxt[0], hB * u_prv[0]);
        const float z1 = fmaf(h, u_own[1], z4.y) + fmaf(hA, u_nxt[1], hB * u_prv[1]);
        const float z2 = fmaf(h, u_own[2], z4.z) + fmaf(hA, u_nxt[2], hB * u_prv[2]);
        const float z3 = fmaf(h, u_own[3], z4.w) + fmaf(hA, u_nxt[3], hB * u_prv[3]);
        const float ai = sigm_s(z0);
        const float af = sigm_s(z1);
        const float ag = tanh_s(z2);
        const float ao = sigm_s(z3);
        c = fmaf(af, c, ai * ag);
        h = ao * tanh_n(c);
        hA = qperm<QPA>(h);
        hB = qperm<QPB>(h);
    };
    auto scan32 = [&](const float* zb) {
        #pragma unroll
        for (int tt = 0; tt < TCH; ++tt) {
            const float4 z4 = *reinterpret_cast<const float4*>(zb + tt * TSTR + e8 * ESTR + m * 4);
            comp(z4);
        }
    };

    // ---- staging: issue-early (global float4) / convert+write-late (bf16 A-frags) ----
    float4 v[PPT];
    auto stage_issue = [&](int ck) {
        const int t0 = ck * TCH;
        #pragma unroll
        for (int i = 0; i < PPT; ++i) {
            const int piece = i * NTHR + tid;
            const int row = piece >> 4, g = piece & 15;
            v[i] = *reinterpret_cast<const float4*>(
                x + ((size_t)(b0 + (row >> 5)) * T_SZ + (t0 + (row & 31))) * F_SZ + (g << 2));
        }
    };
    auto stage_write = [&](int buf) {
        #pragma unroll
        for (int i = 0; i < PPT; ++i) {
            const int piece = i * NTHR + tid;
            const int row = piece >> 4, g = piece & 15;
            // A-frag position: Mtile=row>>4, Ktile=g>>3, lane=(row&15)|((g&3)<<4), h=(g>>2)&1
            const int u_off = ((row >> 4) * 2 + (g >> 3)) * 256
                            + (((row & 15) | ((g & 3) << 4)) << 2) + ((g >> 2) & 1) * 2;
            uint2 pk;
            pk.x = (unsigned)f2bf(v[i].x) | ((unsigned)f2bf(v[i].y) << 16);
            pk.y = (unsigned)f2bf(v[i].z) | ((unsigned)f2bf(v[i].w) << 16);
            *reinterpret_cast<uint2*>(&xfrag[buf][u_off]) = pk;
        }
    };

    // ---- prologue: stage chunk 0 ----
    stage_issue(0);
    stage_write(0);
    __syncthreads();

    // ---- pipeline: issue(k+1) | MFMA z(k) | scan(k-1) | write(k+1) | barrier ----
    for (int k = 0; k < NCHK; ++k) {
        const int cur = k & 1;
        if (k + 1 < NCHK) stage_issue(k + 1);

        if (wv == 1) {
            #pragma unroll
            for (int mt = 0; mt < MT; ++mt) {
                f32x4 acc = { bias_s, bias_s, bias_s, bias_s };
                const short8 a0 = *reinterpret_cast<const short8*>(&xfrag[cur][(mt * 2 + 0) * 256 + (ln << 2)]);
                const short8 a1 = *reinterpret_cast<const short8*>(&xfrag[cur][(mt * 2 + 1) * 256 + (ln << 2)]);
                acc = __builtin_amdgcn_mfma_f32_16x16x32_bf16(a0, bfrag[0], acc, 0, 0, 0);
                acc = __builtin_amdgcn_mfma_f32_16x16x32_bf16(a1, bfrag[1], acc, 0, 0, 0);
                const int rbase = mt * 16 + 4 * (ln >> 4);
                #pragma unroll
                for (int r = 0; r < 4; ++r) {
                    const int rr = rbase + r;                 // row = b*32 + t
                    zbuf[cur][(rr & 31) * TSTR + (rr >> 5) * ESTR + n] = acc[r];
                }
            }
        } else if (k > 0) {
            scan32(zbuf[cur ^ 1]);
        }

        if (k + 1 < NCHK) stage_write(cur ^ 1);
        __syncthreads();
    }

    // ---- epilogue: scan last chunk + dense head ----
    if (wv == 0) {
        scan32(zbuf[(NCHK - 1) & 1]);
        if (ln < 16 && lk == 0) {
            const float logit = bdp[0] + h * Wd[m] + hA * Wd[mn] + hB * Wd[mp];
            out[b0 + e8] = sigm_n(logit);
        }
    }
}

extern "C" void kernel_launch(void* const* d_in, const int* in_sizes, int n_in,
                              void* d_out, int out_size, void* d_ws, size_t ws_size,
                              hipStream_t stream) {
    (void)in_sizes; (void)n_in; (void)out_size; (void)d_ws; (void)ws_size;
    const float* x  = (const float*)d_in[0];
    const float* W  = (const float*)d_in[1];
    const float* U  = (const float*)d_in[2];
    const float* b  = (const float*)d_in[3];
    const float* Wd = (const float*)d_in[4];
    const float* bd = (const float*)d_in[5];
    float* out = (float*)d_out;

    lstm_mfma<<<NBLK, NTHR, 0, stream>>>(x, W, U, b, Wd, bd, out);
}